// Round 1
// baseline (298.650 us; speedup 1.0000x reference)
//
#include <hip/hip_runtime.h>

#define B_ 8
#define C_ 19
#define H_ 512
#define W_ 512
#define HW_ (H_*W_)

#define HALO   20
#define INTR   8             // interior rows per strip
#define WIN    48            // HALO + INTR + HALO
#define NSTRIP 64            // 64*8 = 512
#define CG_    5             // ceil(19/4) class groups for dilate kernel

typedef unsigned long long u64;

#define MASKS_BYTES 4980736ULL          // 8*19*4096*8
#define SDF_BYTES   39845888ULL         // 8*19*512*512

// ---------- pass A: bit-pack target into per-class masks ---------------------
__global__ __launch_bounds__(256) void mask_kernel(const int* __restrict__ target,
                                                   u64* __restrict__ masks) {
    __shared__ u64 mlds[64][21];
    const int blk  = blockIdx.x;          // 512 blocks, 64 per image
    const int b    = blk >> 6;
    const int base = (blk & 63) * 64;     // first word within image
    const int tid  = threadIdx.x;
    const int lane = tid & 63, wv = tid >> 6;
    const int* tgt = target + b * HW_;
    for (int t = 0; t < 16; ++t) {
        const int cl = wv * 16 + t;       // chunk-local word 0..63
        const int x  = tgt[(base + cl) * 64 + lane];
        u64 keep = 0;
        #pragma unroll
        for (int c = 0; c < C_; ++c) {
            u64 m = __ballot(x == c);
            if (lane == c) keep = m;
        }
        if (lane < C_) mlds[cl][lane] = keep;
    }
    __syncthreads();
    for (int idx = tid; idx < C_ * 64; idx += 256) {
        const int c = idx >> 6, wl = idx & 63;
        masks[((size_t)b * C_ + c) * 4096 + base + wl] = mlds[wl][c];
    }
}

// ---------- pass B (fast path): per-(b,strip,class) dilation -----------------
// One wave = ONE class window (48x512 bits in registers). 4 waves/block cover
// 4 consecutive classes of the same strip; grid = 8*64*5 = 2560 blocks
// (9728 active waves vs 2048 in the fused version -> 4.75x more parallelism
// for the latency-bound shfl-chain). Interior sdf bytes staged in 16 KB LDS,
// then cooperatively written coalesced to global.
__global__ __launch_bounds__(256) void dilate_kernel(const u64* __restrict__ masks,
                                                     unsigned char* __restrict__ sdf) {
    __shared__ unsigned char sdfl[4 * INTR * W_];   // 4 classes * 8*512 = 16384 B
    const int blk   = blockIdx.x;          // 0..2559
    const int cg    = blk % CG_;
    const int rem   = blk / CG_;
    const int strip = rem & 63;
    const int b     = rem >> 6;
    const int tid   = threadIdx.x;
    const int wv    = tid >> 6, lane = tid & 63;
    const int w     = lane & 7, g = lane >> 3;
    const int gytop = strip * INTR - HALO; // global row of window row 0
    const int c     = cg * 4 + wv;         // this wave's class (wave-uniform)

    if (c < C_) {
        const u64* mk = masks + ((size_t)b * C_ + c) * 4096;
        u64 cov[6], h[6], iso[6], pl[6][5];

        // ---- load own 6 mask rows (zero outside image)
        #pragma unroll
        for (int i = 0; i < 6; ++i) {
            const int gy = gytop + g * 6 + i;
            cov[i] = (gy >= 0 && gy < H_) ? mk[gy * 8 + w] : 0;
            iso[i] = 0;
            #pragma unroll
            for (int j = 0; j < 5; ++j) pl[i][j] = 0;
        }

        // ---- build no-center spread nc and full spread h of cov
        u64 nc[6];
        {
            unsigned mp = 0, lp = 0;
            #pragma unroll
            for (int i = 0; i < 6; ++i) {
                mp |= (unsigned)(cov[i] >> 63) << i;
                lp |= ((unsigned)cov[i] & 1) << i;
            }
            unsigned fl = __shfl_up(mp, 1);   if (w == 0) fl = 0;
            unsigned fr = __shfl_down(lp, 1); if (w == 7) fr = 0;
            #pragma unroll
            for (int i = 0; i < 6; ++i) {
                nc[i] = (cov[i] << 1) | (cov[i] >> 1) | (u64)((fl >> i) & 1) | ((u64)((fr >> i) & 1) << 63);
                h[i]  = nc[i] | cov[i];
            }
        }

        // ---- step 1: exclude-center neighbor set (iso), then union
        bool active;
        {
            u64 hup = __shfl_up(h[5], 8);   if (g == 0) hup = 0;
            u64 hdn = __shfl_down(h[0], 8); if (g == 7) hdn = 0;
            u64 d[6], diffw = 0;
            #pragma unroll
            for (int i = 0; i < 6; ++i) {
                const u64 up  = (i > 0) ? h[i - 1] : hup;
                const u64 dn  = (i < 5) ? h[i + 1] : hdn;
                const u64 nbr = nc[i] | up | dn;
                iso[i] = cov[i] & ~nbr;
                const u64 nb = nbr & ~cov[i];
                pl[i][0] = nb;               // step 1 = 0b00001
                d[i] = cov[i] | nbr;
                diffw |= nb;
                cov[i] = d[i];
            }
            // rebuild h from d
            unsigned mp = 0, lp = 0;
            #pragma unroll
            for (int i = 0; i < 6; ++i) {
                mp |= (unsigned)(cov[i] >> 63) << i;
                lp |= ((unsigned)cov[i] & 1) << i;
            }
            unsigned fl = __shfl_up(mp, 1);   if (w == 0) fl = 0;
            unsigned fr = __shfl_down(lp, 1); if (w == 7) fr = 0;
            #pragma unroll
            for (int i = 0; i < 6; ++i)
                h[i] = cov[i] | (cov[i] << 1) | (cov[i] >> 1) | (u64)((fl >> i) & 1) | ((u64)((fr >> i) & 1) << 63);
            active = __any(diffw != 0);
        }

        // ---- steps 2..19: d[r] = h[r-1]|h[r]|h[r+1]; wave-wide early exit
        if (active) {
            #pragma unroll
            for (int s = 2; s <= 19; ++s) {
                u64 hup = __shfl_up(h[5], 8);   if (g == 0) hup = 0;
                u64 hdn = __shfl_down(h[0], 8); if (g == 7) hdn = 0;
                u64 diffw = 0;
                #pragma unroll
                for (int i = 0; i < 6; ++i) {
                    const u64 up = (i > 0) ? h[i - 1] : hup;
                    const u64 dn = (i < 5) ? h[i + 1] : hdn;
                    const u64 d  = up | h[i] | dn;
                    const u64 nb = d ^ cov[i];   // newly covered (monotone)
                    diffw |= nb;
                    if (s & 1)  pl[i][0] |= nb;
                    if (s & 2)  pl[i][1] |= nb;
                    if (s & 4)  pl[i][2] |= nb;
                    if (s & 8)  pl[i][3] |= nb;
                    if (s & 16) pl[i][4] |= nb;
                    cov[i] = d;
                }
                if (!__any(diffw != 0)) break;
                if (s < 19) {
                    unsigned mp = 0, lp = 0;
                    #pragma unroll
                    for (int i = 0; i < 6; ++i) {
                        mp |= (unsigned)(cov[i] >> 63) << i;
                        lp |= ((unsigned)cov[i] & 1) << i;
                    }
                    unsigned fl = __shfl_up(mp, 1);   if (w == 0) fl = 0;
                    unsigned fr = __shfl_down(lp, 1); if (w == 7) fr = 0;
                    #pragma unroll
                    for (int i = 0; i < 6; ++i)
                        h[i] = cov[i] | (cov[i] << 1) | (cov[i] >> 1) | (u64)((fl >> i) & 1) | ((u64)((fr >> i) & 1) << 63);
                }
            }
        }

        // ---- epilogue: interior rows -> bytes -> LDS (own class slot = wv)
        #pragma unroll
        for (int i = 0; i < 6; ++i) {
            const int lr = g * 6 + i;
            if (lr < HALO || lr >= HALO + INTR) continue;
            pl[i][0] |= iso[i];              // isolated fg: 0 -> 1
            const u64 m = ~cov[i];           // never covered -> 20 = 0b10100
            pl[i][2] |= m;
            pl[i][4] |= m;
            u64* dst = (u64*)&sdfl[(wv * INTR + (lr - HALO)) * W_ + w * 64];
            #pragma unroll
            for (int g2 = 0; g2 < 8; ++g2) {
                u64 x = 0;
                #pragma unroll
                for (int j = 0; j < 5; ++j)
                    x |= ((pl[i][j] >> (8 * g2)) & 0xFFULL) << (8 * j);
                u64 t;
                t = (x ^ (x >> 7))  & 0x00AA00AA00AA00AAULL; x ^= t ^ (t << 7);
                t = (x ^ (x >> 14)) & 0x0000CCCC0000CCCCULL; x ^= t ^ (t << 14);
                t = (x ^ (x >> 28)) & 0x00000000F0F0F0F0ULL; x ^= t ^ (t << 28);
                dst[g2] = x;                 // byte p = value of pixel g2*8+p
            }
        }
    }
    __syncthreads();

    // ---- cooperative coalesced LDS -> global copy (16B per thread per iter)
    for (int idx = tid; idx < 4 * INTR * W_ / 16; idx += 256) {
        const int cc = idx >> 8;            // class within group (256 x 16B each)
        const int cl = cg * 4 + cc;
        if (cl >= C_) continue;
        const int off = (idx & 255) << 4;   // byte offset within the 4 KB slab
        *(uint4*)(sdf + ((size_t)b * C_ + cl) * HW_ + (size_t)strip * INTR * W_ + off) =
            *(const uint4*)(&sdfl[cc * (INTR * W_) + off]);
    }
}

// ---------- pass C (fast path): pure streaming loss --------------------------
// 2048 blocks x 256 threads; thread owns one float4 pixel-quad, loops classes.
// Reads pred (159.4 MB) + sdf (39.8 MB) once; BW-bound by design.
__global__ __launch_bounds__(256) void loss_kernel(const float* __restrict__ pred,
                                                   const unsigned char* __restrict__ sdf,
                                                   float* __restrict__ out) {
    __shared__ float part[4];
    const int tid = threadIdx.x;
    const size_t q = (size_t)blockIdx.x * 256 + tid;   // quad index, 0..524287
    const int b = (int)(q >> 16);                      // 65536 quads per image
    const int p = ((int)q & 65535) << 2;               // pixel within image
    const float* pb = pred + (size_t)b * C_ * HW_ + p;
    const unsigned char* sb = sdf + (size_t)b * C_ * HW_ + p;
    float4 den = {0.f, 0.f, 0.f, 0.f};
    float4 num = {0.f, 0.f, 0.f, 0.f};
    #pragma unroll
    for (int c = 0; c < C_; ++c) {
        const float4 v  = *(const float4*)(pb + (size_t)c * HW_);
        const uchar4 sv = *(const uchar4*)(sb + (size_t)c * HW_);
        const float e0 = __expf(v.x), e1 = __expf(v.y);
        const float e2 = __expf(v.z), e3 = __expf(v.w);
        den.x += e0; den.y += e1; den.z += e2; den.w += e3;
        num.x = fmaf(e0, (float)sv.x, num.x);
        num.y = fmaf(e1, (float)sv.y, num.y);
        num.z = fmaf(e2, (float)sv.z, num.z);
        num.w = fmaf(e3, (float)sv.w, num.w);
    }
    float acc = num.x / den.x + num.y / den.y + num.z / den.z + num.w / den.w;
    #pragma unroll
    for (int off = 32; off > 0; off >>= 1) acc += __shfl_down(acc, off);
    if ((tid & 63) == 0) part[tid >> 6] = acc;
    __syncthreads();
    if (tid == 0) {
        float s = (part[0] + part[1]) + (part[2] + part[3]);
        atomicAdd(out, s * (1.0f / 39845888.0f));   // / (B*C*H*W)
    }
}

// ---------- fallback: original fused kernel (used only if ws too small) ------
__global__ __launch_bounds__(256, 2) void fused_kernel(const u64* __restrict__ masks,
                                                       const float* __restrict__ pred,
                                                       float* __restrict__ out) {
    __shared__ unsigned char sdfl[C_ * INTR * W_];   // 19*8*512 = 77824 B
    __shared__ float part[4];
    const int blk   = blockIdx.x;          // 0..511
    const int strip = blk & 63;
    const int b     = blk >> 6;
    const int tid   = threadIdx.x;
    const int wv    = tid >> 6, lane = tid & 63;
    const int w     = lane & 7, g = lane >> 3;
    const int gytop = strip * INTR - HALO; // global row of window row 0

    for (int c = wv; c < C_; c += 4) {
        const u64* mk = masks + ((size_t)b * C_ + c) * 4096;
        u64 cov[6], h[6], iso[6], pl[6][5];

        #pragma unroll
        for (int i = 0; i < 6; ++i) {
            const int gy = gytop + g * 6 + i;
            cov[i] = (gy >= 0 && gy < H_) ? mk[gy * 8 + w] : 0;
            iso[i] = 0;
            #pragma unroll
            for (int j = 0; j < 5; ++j) pl[i][j] = 0;
        }

        u64 nc[6];
        {
            unsigned mp = 0, lp = 0;
            #pragma unroll
            for (int i = 0; i < 6; ++i) {
                mp |= (unsigned)(cov[i] >> 63) << i;
                lp |= ((unsigned)cov[i] & 1) << i;
            }
            unsigned fl = __shfl_up(mp, 1);   if (w == 0) fl = 0;
            unsigned fr = __shfl_down(lp, 1); if (w == 7) fr = 0;
            #pragma unroll
            for (int i = 0; i < 6; ++i) {
                nc[i] = (cov[i] << 1) | (cov[i] >> 1) | (u64)((fl >> i) & 1) | ((u64)((fr >> i) & 1) << 63);
                h[i]  = nc[i] | cov[i];
            }
        }

        bool active;
        {
            u64 hup = __shfl_up(h[5], 8);   if (g == 0) hup = 0;
            u64 hdn = __shfl_down(h[0], 8); if (g == 7) hdn = 0;
            u64 d[6], diffw = 0;
            #pragma unroll
            for (int i = 0; i < 6; ++i) {
                const u64 up  = (i > 0) ? h[i - 1] : hup;
                const u64 dn  = (i < 5) ? h[i + 1] : hdn;
                const u64 nbr = nc[i] | up | dn;
                iso[i] = cov[i] & ~nbr;
                const u64 nb = nbr & ~cov[i];
                pl[i][0] = nb;
                d[i] = cov[i] | nbr;
                diffw |= nb;
                cov[i] = d[i];
            }
            unsigned mp = 0, lp = 0;
            #pragma unroll
            for (int i = 0; i < 6; ++i) {
                mp |= (unsigned)(cov[i] >> 63) << i;
                lp |= ((unsigned)cov[i] & 1) << i;
            }
            unsigned fl = __shfl_up(mp, 1);   if (w == 0) fl = 0;
            unsigned fr = __shfl_down(lp, 1); if (w == 7) fr = 0;
            #pragma unroll
            for (int i = 0; i < 6; ++i)
                h[i] = cov[i] | (cov[i] << 1) | (cov[i] >> 1) | (u64)((fl >> i) & 1) | ((u64)((fr >> i) & 1) << 63);
            active = __any(diffw != 0);
        }

        if (active) {
            #pragma unroll
            for (int s = 2; s <= 19; ++s) {
                u64 hup = __shfl_up(h[5], 8);   if (g == 0) hup = 0;
                u64 hdn = __shfl_down(h[0], 8); if (g == 7) hdn = 0;
                u64 diffw = 0;
                #pragma unroll
                for (int i = 0; i < 6; ++i) {
                    const u64 up = (i > 0) ? h[i - 1] : hup;
                    const u64 dn = (i < 5) ? h[i + 1] : hdn;
                    const u64 d  = up | h[i] | dn;
                    const u64 nb = d ^ cov[i];
                    diffw |= nb;
                    if (s & 1)  pl[i][0] |= nb;
                    if (s & 2)  pl[i][1] |= nb;
                    if (s & 4)  pl[i][2] |= nb;
                    if (s & 8)  pl[i][3] |= nb;
                    if (s & 16) pl[i][4] |= nb;
                    cov[i] = d;
                }
                if (!__any(diffw != 0)) break;
                if (s < 19) {
                    unsigned mp = 0, lp = 0;
                    #pragma unroll
                    for (int i = 0; i < 6; ++i) {
                        mp |= (unsigned)(cov[i] >> 63) << i;
                        lp |= ((unsigned)cov[i] & 1) << i;
                    }
                    unsigned fl = __shfl_up(mp, 1);   if (w == 0) fl = 0;
                    unsigned fr = __shfl_down(lp, 1); if (w == 7) fr = 0;
                    #pragma unroll
                    for (int i = 0; i < 6; ++i)
                        h[i] = cov[i] | (cov[i] << 1) | (cov[i] >> 1) | (u64)((fl >> i) & 1) | ((u64)((fr >> i) & 1) << 63);
                }
            }
        }

        #pragma unroll
        for (int i = 0; i < 6; ++i) {
            const int lr = g * 6 + i;
            if (lr < HALO || lr >= HALO + INTR) continue;
            pl[i][0] |= iso[i];
            const u64 m = ~cov[i];
            pl[i][2] |= m;
            pl[i][4] |= m;
            u64* dst = (u64*)&sdfl[(c * INTR + (lr - HALO)) * W_ + w * 64];
            #pragma unroll
            for (int g2 = 0; g2 < 8; ++g2) {
                u64 x = 0;
                #pragma unroll
                for (int j = 0; j < 5; ++j)
                    x |= ((pl[i][j] >> (8 * g2)) & 0xFFULL) << (8 * j);
                u64 t;
                t = (x ^ (x >> 7))  & 0x00AA00AA00AA00AAULL; x ^= t ^ (t << 7);
                t = (x ^ (x >> 14)) & 0x0000CCCC0000CCCCULL; x ^= t ^ (t << 14);
                t = (x ^ (x >> 28)) & 0x00000000F0F0F0F0ULL; x ^= t ^ (t << 28);
                dst[g2] = x;
            }
        }
    }
    __syncthreads();

    float acc = 0.f;
    const float* pb = pred + (size_t)b * C_ * HW_ + (size_t)strip * INTR * W_;
    #pragma unroll
    for (int k = 0; k < 4; ++k) {
        const int p = k * 1024 + tid * 4;
        float4 den = {0.f, 0.f, 0.f, 0.f};
        float4 num = {0.f, 0.f, 0.f, 0.f};
        #pragma unroll
        for (int c = 0; c < C_; ++c) {
            const float4 v  = *(const float4*)(pb + (size_t)c * HW_ + p);
            const uchar4 sv = *(const uchar4*)&sdfl[c * 4096 + p];
            const float e0 = __expf(v.x), e1 = __expf(v.y);
            const float e2 = __expf(v.z), e3 = __expf(v.w);
            den.x += e0; den.y += e1; den.z += e2; den.w += e3;
            num.x = fmaf(e0, (float)sv.x, num.x);
            num.y = fmaf(e1, (float)sv.y, num.y);
            num.z = fmaf(e2, (float)sv.z, num.z);
            num.w = fmaf(e3, (float)sv.w, num.w);
        }
        acc += num.x / den.x + num.y / den.y + num.z / den.z + num.w / den.w;
    }

    #pragma unroll
    for (int off = 32; off > 0; off >>= 1) acc += __shfl_down(acc, off);
    if ((tid & 63) == 0) part[tid >> 6] = acc;
    __syncthreads();
    if (tid == 0) {
        float s = (part[0] + part[1]) + (part[2] + part[3]);
        atomicAdd(out, s * (1.0f / 39845888.0f));
    }
}

extern "C" void kernel_launch(void* const* d_in, const int* in_sizes, int n_in,
                              void* d_out, int out_size, void* d_ws, size_t ws_size,
                              hipStream_t stream) {
    const float* pred   = (const float*)d_in[0];
    const int*   target = (const int*)d_in[1];
    u64* masks = (u64*)d_ws;                               // 4,980,736 B
    float* out = (float*)d_out;

    hipMemsetAsync(out, 0, sizeof(float), stream);         // harness poisons d_out
    mask_kernel<<<512, 256, 0, stream>>>(target, masks);

    if (ws_size >= MASKS_BYTES + SDF_BYTES) {
        // fast path: split latency-bound dilation from BW-bound loss stream
        unsigned char* sdf = (unsigned char*)d_ws + MASKS_BYTES;   // 39,845,888 B
        dilate_kernel<<<B_ * NSTRIP * CG_, 256, 0, stream>>>(masks, sdf);
        loss_kernel<<<(B_ * HW_ / 4) / 256, 256, 0, stream>>>(pred, sdf, out);
    } else {
        // fallback: proven fused kernel (baseline performance)
        fused_kernel<<<B_ * NSTRIP, 256, 0, stream>>>(masks, pred, out);
    }
}

// Round 4
// 292.181 us; speedup vs baseline: 1.0221x; 1.0221x over previous
//
#include <hip/hip_runtime.h>

#define B_ 8
#define C_ 19
#define H_ 512
#define W_ 512
#define HW_ (H_*W_)

#define HALO   20
#define INTR   8             // interior rows per strip
#define WIN    48            // HALO + INTR + HALO
#define NSTRIP 64            // 64*8 = 512
#define CG_    5             // ceil(19/4) class groups for dilate kernel

typedef unsigned long long u64;
typedef float f32x4 __attribute__((ext_vector_type(4)));   // builtin vec type:
// __builtin_nontemporal_load requires scalar/builtin-vector, not HIP float4.

#define MASKS_BYTES 4980736ULL          // 8*19*4096*8
#define SDF_BYTES   39845888ULL         // 8*19*512*512

// ---------- pass A: bit-pack target into per-class masks ---------------------
// Also zeroes the (harness-poisoned) output scalar: saves one graph dispatch.
__global__ __launch_bounds__(256) void mask_kernel(const int* __restrict__ target,
                                                   u64* __restrict__ masks,
                                                   float* __restrict__ out) {
    __shared__ u64 mlds[64][21];
    const int blk  = blockIdx.x;          // 512 blocks, 64 per image
    const int b    = blk >> 6;
    const int base = (blk & 63) * 64;     // first word within image
    const int tid  = threadIdx.x;
    const int lane = tid & 63, wv = tid >> 6;
    if (blk == 0 && tid == 0) out[0] = 0.f;   // runs before loss_kernel's atomics
    const int* tgt = target + b * HW_;
    for (int t = 0; t < 16; ++t) {
        const int cl = wv * 16 + t;       // chunk-local word 0..63
        const int x  = tgt[(base + cl) * 64 + lane];
        u64 keep = 0;
        #pragma unroll
        for (int c = 0; c < C_; ++c) {
            u64 m = __ballot(x == c);
            if (lane == c) keep = m;
        }
        if (lane < C_) mlds[cl][lane] = keep;
    }
    __syncthreads();
    for (int idx = tid; idx < C_ * 64; idx += 256) {
        const int c = idx >> 6, wl = idx & 63;
        masks[((size_t)b * C_ + c) * 4096 + base + wl] = mlds[wl][c];
    }
}

// ---------- pass B: per-(b,strip,class) dilation -----------------------------
// One wave = ONE class window (48x512 bits in registers). 4 waves/block cover
// 4 consecutive classes of the same strip; grid = 8*64*5 = 2560 blocks.
// Interior sdf bytes staged in 16 KB LDS, then written coalesced to global.
__global__ __launch_bounds__(256) void dilate_kernel(const u64* __restrict__ masks,
                                                     unsigned char* __restrict__ sdf) {
    __shared__ unsigned char sdfl[4 * INTR * W_];   // 4 classes * 8*512 = 16384 B
    const int blk   = blockIdx.x;          // 0..2559
    const int cg    = blk % CG_;
    const int rem   = blk / CG_;
    const int strip = rem & 63;
    const int b     = rem >> 6;
    const int tid   = threadIdx.x;
    const int wv    = tid >> 6, lane = tid & 63;
    const int w     = lane & 7, g = lane >> 3;
    const int gytop = strip * INTR - HALO; // global row of window row 0
    const int c     = cg * 4 + wv;         // this wave's class (wave-uniform)

    if (c < C_) {
        const u64* mk = masks + ((size_t)b * C_ + c) * 4096;
        u64 cov[6], h[6], iso[6], pl[6][5];

        // ---- load own 6 mask rows (zero outside image)
        #pragma unroll
        for (int i = 0; i < 6; ++i) {
            const int gy = gytop + g * 6 + i;
            cov[i] = (gy >= 0 && gy < H_) ? mk[gy * 8 + w] : 0;
            iso[i] = 0;
            #pragma unroll
            for (int j = 0; j < 5; ++j) pl[i][j] = 0;
        }

        // ---- build no-center spread nc and full spread h of cov
        u64 nc[6];
        {
            unsigned mp = 0, lp = 0;
            #pragma unroll
            for (int i = 0; i < 6; ++i) {
                mp |= (unsigned)(cov[i] >> 63) << i;
                lp |= ((unsigned)cov[i] & 1) << i;
            }
            unsigned fl = __shfl_up(mp, 1);   if (w == 0) fl = 0;
            unsigned fr = __shfl_down(lp, 1); if (w == 7) fr = 0;
            #pragma unroll
            for (int i = 0; i < 6; ++i) {
                nc[i] = (cov[i] << 1) | (cov[i] >> 1) | (u64)((fl >> i) & 1) | ((u64)((fr >> i) & 1) << 63);
                h[i]  = nc[i] | cov[i];
            }
        }

        // ---- step 1: exclude-center neighbor set (iso), then union
        bool active;
        {
            u64 hup = __shfl_up(h[5], 8);   if (g == 0) hup = 0;
            u64 hdn = __shfl_down(h[0], 8); if (g == 7) hdn = 0;
            u64 d[6], diffw = 0;
            #pragma unroll
            for (int i = 0; i < 6; ++i) {
                const u64 up  = (i > 0) ? h[i - 1] : hup;
                const u64 dn  = (i < 5) ? h[i + 1] : hdn;
                const u64 nbr = nc[i] | up | dn;
                iso[i] = cov[i] & ~nbr;
                const u64 nb = nbr & ~cov[i];
                pl[i][0] = nb;               // step 1 = 0b00001
                d[i] = cov[i] | nbr;
                diffw |= nb;
                cov[i] = d[i];
            }
            // rebuild h from d
            unsigned mp = 0, lp = 0;
            #pragma unroll
            for (int i = 0; i < 6; ++i) {
                mp |= (unsigned)(cov[i] >> 63) << i;
                lp |= ((unsigned)cov[i] & 1) << i;
            }
            unsigned fl = __shfl_up(mp, 1);   if (w == 0) fl = 0;
            unsigned fr = __shfl_down(lp, 1); if (w == 7) fr = 0;
            #pragma unroll
            for (int i = 0; i < 6; ++i)
                h[i] = cov[i] | (cov[i] << 1) | (cov[i] >> 1) | (u64)((fl >> i) & 1) | ((u64)((fr >> i) & 1) << 63);
            active = __any(diffw != 0);
        }

        // ---- steps 2..19: d[r] = h[r-1]|h[r]|h[r+1]; wave-wide early exit
        if (active) {
            #pragma unroll
            for (int s = 2; s <= 19; ++s) {
                u64 hup = __shfl_up(h[5], 8);   if (g == 0) hup = 0;
                u64 hdn = __shfl_down(h[0], 8); if (g == 7) hdn = 0;
                u64 diffw = 0;
                #pragma unroll
                for (int i = 0; i < 6; ++i) {
                    const u64 up = (i > 0) ? h[i - 1] : hup;
                    const u64 dn = (i < 5) ? h[i + 1] : hdn;
                    const u64 d  = up | h[i] | dn;
                    const u64 nb = d ^ cov[i];   // newly covered (monotone)
                    diffw |= nb;
                    if (s & 1)  pl[i][0] |= nb;
                    if (s & 2)  pl[i][1] |= nb;
                    if (s & 4)  pl[i][2] |= nb;
                    if (s & 8)  pl[i][3] |= nb;
                    if (s & 16) pl[i][4] |= nb;
                    cov[i] = d;
                }
                if (!__any(diffw != 0)) break;
                if (s < 19) {
                    unsigned mp = 0, lp = 0;
                    #pragma unroll
                    for (int i = 0; i < 6; ++i) {
                        mp |= (unsigned)(cov[i] >> 63) << i;
                        lp |= ((unsigned)cov[i] & 1) << i;
                    }
                    unsigned fl = __shfl_up(mp, 1);   if (w == 0) fl = 0;
                    unsigned fr = __shfl_down(lp, 1); if (w == 7) fr = 0;
                    #pragma unroll
                    for (int i = 0; i < 6; ++i)
                        h[i] = cov[i] | (cov[i] << 1) | (cov[i] >> 1) | (u64)((fl >> i) & 1) | ((u64)((fr >> i) & 1) << 63);
                }
            }
        }

        // ---- epilogue: interior rows -> bytes -> LDS (own class slot = wv)
        #pragma unroll
        for (int i = 0; i < 6; ++i) {
            const int lr = g * 6 + i;
            if (lr < HALO || lr >= HALO + INTR) continue;
            pl[i][0] |= iso[i];              // isolated fg: 0 -> 1
            const u64 m = ~cov[i];           // never covered -> 20 = 0b10100
            pl[i][2] |= m;
            pl[i][4] |= m;
            u64* dst = (u64*)&sdfl[(wv * INTR + (lr - HALO)) * W_ + w * 64];
            #pragma unroll
            for (int g2 = 0; g2 < 8; ++g2) {
                u64 x = 0;
                #pragma unroll
                for (int j = 0; j < 5; ++j)
                    x |= ((pl[i][j] >> (8 * g2)) & 0xFFULL) << (8 * j);
                u64 t;
                t = (x ^ (x >> 7))  & 0x00AA00AA00AA00AAULL; x ^= t ^ (t << 7);
                t = (x ^ (x >> 14)) & 0x0000CCCC0000CCCCULL; x ^= t ^ (t << 14);
                t = (x ^ (x >> 28)) & 0x00000000F0F0F0F0ULL; x ^= t ^ (t << 28);
                dst[g2] = x;                 // byte p = value of pixel g2*8+p
            }
        }
    }
    __syncthreads();

    // ---- cooperative coalesced LDS -> global copy (16B per thread per iter)
    for (int idx = tid; idx < 4 * INTR * W_ / 16; idx += 256) {
        const int cc = idx >> 8;            // class within group (256 x 16B each)
        const int cl = cg * 4 + cc;
        if (cl >= C_) continue;
        const int off = (idx & 255) << 4;   // byte offset within the 4 KB slab
        *(uint4*)(sdf + ((size_t)b * C_ + cl) * HW_ + (size_t)strip * INTR * W_ + off) =
            *(const uint4*)(&sdfl[cc * (INTR * W_) + off]);
    }
}

// ---------- pass C: pure streaming loss --------------------------------------
// 2048 blocks x 256 threads (88 VGPR -> wave-slot-limited 32 waves/CU).
// Thread owns one float4 pixel-quad, loops classes. pred is dead-after-read:
// non-temporal loads keep it from evicting the freshly-written sdf from L2/L3.
__global__ __launch_bounds__(256) void loss_kernel(const float* __restrict__ pred,
                                                   const unsigned char* __restrict__ sdf,
                                                   float* __restrict__ out) {
    __shared__ float part[4];
    const int tid = threadIdx.x;
    const size_t q = (size_t)blockIdx.x * 256 + tid;   // quad index, 0..524287
    const int b = (int)(q >> 16);                      // 65536 quads per image
    const int p = ((int)q & 65535) << 2;               // pixel within image
    const float* pb = pred + (size_t)b * C_ * HW_ + p;
    const unsigned char* sb = sdf + (size_t)b * C_ * HW_ + p;
    float den0 = 0.f, den1 = 0.f, den2 = 0.f, den3 = 0.f;
    float num0 = 0.f, num1 = 0.f, num2 = 0.f, num3 = 0.f;
    #pragma unroll
    for (int c = 0; c < C_; ++c) {
        const f32x4 v   = __builtin_nontemporal_load((const f32x4*)(pb + (size_t)c * HW_));
        const uchar4 sv = *(const uchar4*)(sb + (size_t)c * HW_);
        const float e0 = __expf(v[0]), e1 = __expf(v[1]);
        const float e2 = __expf(v[2]), e3 = __expf(v[3]);
        den0 += e0; den1 += e1; den2 += e2; den3 += e3;
        num0 = fmaf(e0, (float)sv.x, num0);
        num1 = fmaf(e1, (float)sv.y, num1);
        num2 = fmaf(e2, (float)sv.z, num2);
        num3 = fmaf(e3, (float)sv.w, num3);
    }
    float acc = num0 / den0 + num1 / den1 + num2 / den2 + num3 / den3;
    #pragma unroll
    for (int off = 32; off > 0; off >>= 1) acc += __shfl_down(acc, off);
    if ((tid & 63) == 0) part[tid >> 6] = acc;
    __syncthreads();
    if (tid == 0) {
        float s = (part[0] + part[1]) + (part[2] + part[3]);
        atomicAdd(out, s * (1.0f / 39845888.0f));   // / (B*C*H*W)
    }
}

// ---------- fallback: original fused kernel (used only if ws too small) ------
__global__ __launch_bounds__(256, 2) void fused_kernel(const u64* __restrict__ masks,
                                                       const float* __restrict__ pred,
                                                       float* __restrict__ out) {
    __shared__ unsigned char sdfl[C_ * INTR * W_];   // 19*8*512 = 77824 B
    __shared__ float part[4];
    const int blk   = blockIdx.x;          // 0..511
    const int strip = blk & 63;
    const int b     = blk >> 6;
    const int tid   = threadIdx.x;
    const int wv    = tid >> 6, lane = tid & 63;
    const int w     = lane & 7, g = lane >> 3;
    const int gytop = strip * INTR - HALO; // global row of window row 0

    for (int c = wv; c < C_; c += 4) {
        const u64* mk = masks + ((size_t)b * C_ + c) * 4096;
        u64 cov[6], h[6], iso[6], pl[6][5];

        #pragma unroll
        for (int i = 0; i < 6; ++i) {
            const int gy = gytop + g * 6 + i;
            cov[i] = (gy >= 0 && gy < H_) ? mk[gy * 8 + w] : 0;
            iso[i] = 0;
            #pragma unroll
            for (int j = 0; j < 5; ++j) pl[i][j] = 0;
        }

        u64 nc[6];
        {
            unsigned mp = 0, lp = 0;
            #pragma unroll
            for (int i = 0; i < 6; ++i) {
                mp |= (unsigned)(cov[i] >> 63) << i;
                lp |= ((unsigned)cov[i] & 1) << i;
            }
            unsigned fl = __shfl_up(mp, 1);   if (w == 0) fl = 0;
            unsigned fr = __shfl_down(lp, 1); if (w == 7) fr = 0;
            #pragma unroll
            for (int i = 0; i < 6; ++i) {
                nc[i] = (cov[i] << 1) | (cov[i] >> 1) | (u64)((fl >> i) & 1) | ((u64)((fr >> i) & 1) << 63);
                h[i]  = nc[i] | cov[i];
            }
        }

        bool active;
        {
            u64 hup = __shfl_up(h[5], 8);   if (g == 0) hup = 0;
            u64 hdn = __shfl_down(h[0], 8); if (g == 7) hdn = 0;
            u64 d[6], diffw = 0;
            #pragma unroll
            for (int i = 0; i < 6; ++i) {
                const u64 up  = (i > 0) ? h[i - 1] : hup;
                const u64 dn  = (i < 5) ? h[i + 1] : hdn;
                const u64 nbr = nc[i] | up | dn;
                iso[i] = cov[i] & ~nbr;
                const u64 nb = nbr & ~cov[i];
                pl[i][0] = nb;
                d[i] = cov[i] | nbr;
                diffw |= nb;
                cov[i] = d[i];
            }
            unsigned mp = 0, lp = 0;
            #pragma unroll
            for (int i = 0; i < 6; ++i) {
                mp |= (unsigned)(cov[i] >> 63) << i;
                lp |= ((unsigned)cov[i] & 1) << i;
            }
            unsigned fl = __shfl_up(mp, 1);   if (w == 0) fl = 0;
            unsigned fr = __shfl_down(lp, 1); if (w == 7) fr = 0;
            #pragma unroll
            for (int i = 0; i < 6; ++i)
                h[i] = cov[i] | (cov[i] << 1) | (cov[i] >> 1) | (u64)((fl >> i) & 1) | ((u64)((fr >> i) & 1) << 63);
            active = __any(diffw != 0);
        }

        if (active) {
            #pragma unroll
            for (int s = 2; s <= 19; ++s) {
                u64 hup = __shfl_up(h[5], 8);   if (g == 0) hup = 0;
                u64 hdn = __shfl_down(h[0], 8); if (g == 7) hdn = 0;
                u64 diffw = 0;
                #pragma unroll
                for (int i = 0; i < 6; ++i) {
                    const u64 up = (i > 0) ? h[i - 1] : hup;
                    const u64 dn = (i < 5) ? h[i + 1] : hdn;
                    const u64 d  = up | h[i] | dn;
                    const u64 nb = d ^ cov[i];
                    diffw |= nb;
                    if (s & 1)  pl[i][0] |= nb;
                    if (s & 2)  pl[i][1] |= nb;
                    if (s & 4)  pl[i][2] |= nb;
                    if (s & 8)  pl[i][3] |= nb;
                    if (s & 16) pl[i][4] |= nb;
                    cov[i] = d;
                }
                if (!__any(diffw != 0)) break;
                if (s < 19) {
                    unsigned mp = 0, lp = 0;
                    #pragma unroll
                    for (int i = 0; i < 6; ++i) {
                        mp |= (unsigned)(cov[i] >> 63) << i;
                        lp |= ((unsigned)cov[i] & 1) << i;
                    }
                    unsigned fl = __shfl_up(mp, 1);   if (w == 0) fl = 0;
                    unsigned fr = __shfl_down(lp, 1); if (w == 7) fr = 0;
                    #pragma unroll
                    for (int i = 0; i < 6; ++i)
                        h[i] = cov[i] | (cov[i] << 1) | (cov[i] >> 1) | (u64)((fl >> i) & 1) | ((u64)((fr >> i) & 1) << 63);
                }
            }
        }

        #pragma unroll
        for (int i = 0; i < 6; ++i) {
            const int lr = g * 6 + i;
            if (lr < HALO || lr >= HALO + INTR) continue;
            pl[i][0] |= iso[i];
            const u64 m = ~cov[i];
            pl[i][2] |= m;
            pl[i][4] |= m;
            u64* dst = (u64*)&sdfl[(c * INTR + (lr - HALO)) * W_ + w * 64];
            #pragma unroll
            for (int g2 = 0; g2 < 8; ++g2) {
                u64 x = 0;
                #pragma unroll
                for (int j = 0; j < 5; ++j)
                    x |= ((pl[i][j] >> (8 * g2)) & 0xFFULL) << (8 * j);
                u64 t;
                t = (x ^ (x >> 7))  & 0x00AA00AA00AA00AAULL; x ^= t ^ (t << 7);
                t = (x ^ (x >> 14)) & 0x0000CCCC0000CCCCULL; x ^= t ^ (t << 14);
                t = (x ^ (x >> 28)) & 0x00000000F0F0F0F0ULL; x ^= t ^ (t << 28);
                dst[g2] = x;
            }
        }
    }
    __syncthreads();

    float acc = 0.f;
    const float* pb = pred + (size_t)b * C_ * HW_ + (size_t)strip * INTR * W_;
    #pragma unroll
    for (int k = 0; k < 4; ++k) {
        const int p = k * 1024 + tid * 4;
        float4 den = {0.f, 0.f, 0.f, 0.f};
        float4 num = {0.f, 0.f, 0.f, 0.f};
        #pragma unroll
        for (int c = 0; c < C_; ++c) {
            const float4 v  = *(const float4*)(pb + (size_t)c * HW_ + p);
            const uchar4 sv = *(const uchar4*)&sdfl[c * 4096 + p];
            const float e0 = __expf(v.x), e1 = __expf(v.y);
            const float e2 = __expf(v.z), e3 = __expf(v.w);
            den.x += e0; den.y += e1; den.z += e2; den.w += e3;
            num.x = fmaf(e0, (float)sv.x, num.x);
            num.y = fmaf(e1, (float)sv.y, num.y);
            num.z = fmaf(e2, (float)sv.z, num.z);
            num.w = fmaf(e3, (float)sv.w, num.w);
        }
        acc += num.x / den.x + num.y / den.y + num.z / den.z + num.w / den.w;
    }

    #pragma unroll
    for (int off = 32; off > 0; off >>= 1) acc += __shfl_down(acc, off);
    if ((tid & 63) == 0) part[tid >> 6] = acc;
    __syncthreads();
    if (tid == 0) {
        float s = (part[0] + part[1]) + (part[2] + part[3]);
        atomicAdd(out, s * (1.0f / 39845888.0f));
    }
}

extern "C" void kernel_launch(void* const* d_in, const int* in_sizes, int n_in,
                              void* d_out, int out_size, void* d_ws, size_t ws_size,
                              hipStream_t stream) {
    const float* pred   = (const float*)d_in[0];
    const int*   target = (const int*)d_in[1];
    u64* masks = (u64*)d_ws;                               // 4,980,736 B
    float* out = (float*)d_out;

    // out-zeroing is folded into mask_kernel (block 0) — no memset dispatch
    mask_kernel<<<512, 256, 0, stream>>>(target, masks, out);

    if (ws_size >= MASKS_BYTES + SDF_BYTES) {
        // fast path: split latency-bound dilation from BW-bound loss stream
        unsigned char* sdf = (unsigned char*)d_ws + MASKS_BYTES;   // 39,845,888 B
        dilate_kernel<<<B_ * NSTRIP * CG_, 256, 0, stream>>>(masks, sdf);
        loss_kernel<<<(B_ * HW_ / 4) / 256, 256, 0, stream>>>(pred, sdf, out);
    } else {
        // fallback: proven fused kernel (baseline performance)
        fused_kernel<<<B_ * NSTRIP, 256, 0, stream>>>(masks, pred, out);
    }
}